// Round 17
// baseline (165.289 us; speedup 1.0000x reference)
//
#include <hip/hip_runtime.h>

#define BATCH    8
#define T_LEN    4096
#define D_DIM    128
#define H_HEADS  4
#define O_DIM    32
#define E_EDGES  65536
#define N_NODES  (BATCH * T_LEN)      // 32768
#define NEG_SLOPE 0.2f
#define ELLCAP   48                   // deg ~ Binom: mean 16, sd 4; 48 = 8 sigma
#define GEMM_BLOCKS 512               // 64 rows each
#define ELL_BLOCKS  16                // 256 dsts each, LDS counters
#define XSTRIDE  144                  // Xb row stride in shorts (288 B, 16B-mult)
#define ATTB_COL 40                   // attB col stride (80 B)
#define ATTB_KT  320                  // attB kt stride (= 8 cols * 40)

typedef __attribute__((ext_vector_type(8))) short short8;
typedef __attribute__((ext_vector_type(4))) float f32x4;

// round-to-nearest-even fp32 -> bf16 bits
__device__ __forceinline__ unsigned int bf16b(float f) {
    unsigned int u = __float_as_uint(f);
    u += 0x7FFFu + ((u >> 16) & 1u);
    return u >> 16;
}
__device__ __forceinline__ unsigned int bf16pack(float lo, float hi) {
    return bf16b(lo) | (bf16b(hi) << 16);
}
__device__ __forceinline__ float bf16f(unsigned short u) {
    return __uint_as_float((unsigned int)u << 16);
}

// ---------------------------------------------------------------------------
// Fused single-dispatch front end:
//   blocks [0,512):   bf16-MFMA GEMM h=X*W + MFMA logits (52 KB LDS, 3/CU).
//                     W transposed in-block (2 coalesced row-loads -> 4 LDS
//                     b32 writes per k-pair task) — no prep kernel needed.
//   blocks [512,528): ELL build, one block per 256 dsts, LDS counters
//                     (aliased into Xb) — no global atomics, no pre-zeroing.
// ---------------------------------------------------------------------------
__launch_bounds__(256)
__global__ void fused_kernel(const float* __restrict__ x,
                             const float* __restrict__ W,
                             const float* __restrict__ attS,
                             const float* __restrict__ attD,
                             const int* __restrict__ ei,
                             unsigned short* __restrict__ hb,
                             float* __restrict__ aS,
                             float* __restrict__ aD,
                             int* __restrict__ cnt,
                             int* __restrict__ ell) {
    __shared__ __align__(16) short Xb[64][XSTRIDE]; // X tile / h staging / lcnt
    __shared__ __align__(16) short Wt[128][136];    // W^T bf16; tail reused
    __shared__ int   s_sh;

    const int tid = threadIdx.x;

    if (blockIdx.x >= GEMM_BLOCKS) {
        // ---------------- ELL build branch (LDS counters) ----------------
        int* lcnt = (int*)&Xb[0][0];              // 256 ints, aliased
        // int64-vs-int32 layout detect (values < 4096 -> odd words all 0)
        if (tid < 64) {
            const int nz = (ei[2 * tid + 1] != 0) ? 1 : 0;
            const unsigned long long b = __ballot(nz);
            if (tid == 0) s_sh = (b == 0ull) ? 1 : 0;
        }
        lcnt[tid] = 0;
        __syncthreads();
        const int sh = s_sh;
        const int d0 = (blockIdx.x - GEMM_BLOCKS) * 256;

        for (int it = 0; it < E_EDGES / 256; ++it) {
            const int j = it * 256 + tid;
            const int d = ei[(E_EDGES + j) << sh];
            if (d >= d0 && d < d0 + 256) {
                const int s = ei[j << sh];
                const int p = atomicAdd(&lcnt[d - d0], 1);  // LDS atomic
                if (p < ELLCAP) ell[d * ELLCAP + p] = s;
            }
        }
        __syncthreads();
        cnt[d0 + tid] = lcnt[tid];                // exact count (may exceed cap)
        return;
    }

    // ---------------- GEMM branch ----------------
    // batch = blk%8 (XCD pin), 64-row tile = blk/8
    const int row0 = (blockIdx.x & 7) * T_LEN + ((blockIdx.x >> 3) << 6);

    // stage X tile (64x128 fp32 -> bf16), coalesced float4 reads
    const float4* X4 = (const float4*)(x + (size_t)row0 * 128);
    #pragma unroll
    for (int i = 0; i < 8; ++i) {
        const int idx = tid + 256 * i;
        const int row = idx >> 5;
        const int c4  = (idx & 31) * 4;
        const float4 v = X4[idx];
        uint2 u;
        u.x = bf16pack(v.x, v.y);
        u.y = bf16pack(v.z, v.w);
        *(uint2*)&Xb[row][c4] = u;
    }

    // transpose-stage W -> Wt bf16 in-block: task = (k-pair kp, col-quad cq);
    // 2 coalesced float4 row loads, 4 b32 LDS writes (Wt[c][2kp],[2kp+1]).
    const float4* W4 = (const float4*)W;
    #pragma unroll
    for (int i = 0; i < 8; ++i) {
        const int idx = tid + 256 * i;            // 2048 tasks
        const int kp  = idx >> 5;                 // 0..63
        const int cq  = idx & 31;                 // 0..31
        const float4 r0 = W4[(2 * kp)     * 32 + cq];
        const float4 r1 = W4[(2 * kp + 1) * 32 + cq];
        const int c0 = cq * 4;
        *(unsigned int*)&Wt[c0 + 0][2 * kp] = bf16pack(r0.x, r1.x);
        *(unsigned int*)&Wt[c0 + 1][2 * kp] = bf16pack(r0.y, r1.y);
        *(unsigned int*)&Wt[c0 + 2][2 * kp] = bf16pack(r0.z, r1.z);
        *(unsigned int*)&Wt[c0 + 3][2 * kp] = bf16pack(r0.w, r1.w);
    }
    __syncthreads();

    const int wv    = tid >> 6;        // wave 0..3 -> rows wv*16..+16
    const int l     = tid & 63;
    const int lr    = l & 15;
    const int lg    = l >> 4;
    const int wrow0 = wv * 16;

    f32x4 acc[8];
    #pragma unroll
    for (int cf = 0; cf < 8; ++cf) acc[cf] = (f32x4){0.f, 0.f, 0.f, 0.f};

    #pragma unroll
    for (int kt = 0; kt < 4; ++kt) {
        const int k0 = kt * 32 + lg * 8;
        const short8 a = *(const short8*)&Xb[wrow0 + lr][k0];
        #pragma unroll
        for (int cf = 0; cf < 8; ++cf) {
            const short8 b = *(const short8*)&Wt[cf * 16 + lr][k0];
            acc[cf] = __builtin_amdgcn_mfma_f32_16x16x32_bf16(a, b, acc[cf], 0, 0, 0);
        }
    }

    __syncthreads();   // all waves done reading Xb (A) and Wt (B)

    // scatter bf16 h into Xb (stride 144 -> rows rotate 8 banks, <=2-way)
    #pragma unroll
    for (int cf = 0; cf < 8; ++cf) {
        #pragma unroll
        for (int r = 0; r < 4; ++r)
            Xb[wrow0 + lg * 4 + r][cf * 16 + lr] = (short)bf16b(acc[cf][r]);
    }

    // build block-diagonal att table in dead Wt space:
    // col 0-3 = attS head col (nonzero iff kt==col), col 4-7 = attD head col-4
    short* attB = &Wt[0][0];
    #pragma unroll
    for (int e = 0; e < 5; ++e) {
        const int idx = tid * 5 + e;              // 1280 entries
        const int kt  = idx / ATTB_KT;
        const int rem = idx - kt * ATTB_KT;
        const int col = rem / ATTB_COL;
        const int kk  = rem - col * ATTB_COL;
        float v = 0.f;
        if (kk < 32) {
            if (col < 4) v = (kt == col)     ? attS[col * 32 + kk]       : 0.f;
            else         v = (kt == col - 4) ? attD[(col - 4) * 32 + kk] : 0.f;
        }
        attB[idx] = (short)bf16b(v);
    }
    __syncthreads();

    // coalesced h stores (1 KB/instruction)
    #pragma unroll
    for (int i = 0; i < 4; ++i) {
        const int idx = tid + 256 * i;            // 1024 chunks of 8 shorts
        const int row = idx >> 4;
        const int off = (idx & 15) * 8;
        *(short8*)&hb[(size_t)(row0 + row) * 128 + off] =
            *(const short8*)&Xb[row][off];
    }

    // logits via MFMA: accL[row][col] = sum_k h[row][k]*attB[col][k]
    f32x4 accL = (f32x4){0.f, 0.f, 0.f, 0.f};
    #pragma unroll
    for (int kt = 0; kt < 4; ++kt) {
        const short8 a2 = *(const short8*)&Xb[wrow0 + lr][kt * 32 + lg * 8];
        const short8 b2 = *(const short8*)&attB[kt * ATTB_KT + (lr & 7) * ATTB_COL + lg * 8];
        accL = __builtin_amdgcn_mfma_f32_16x16x32_bf16(a2, b2, accL, 0, 0, 0);
    }
    if (lr < 8) {
        #pragma unroll
        for (int r = 0; r < 4; ++r) {
            const int row = row0 + wrow0 + lg * 4 + r;
            if (lr < 4) aS[(size_t)row * 4 + lr]       = accL[r];
            else        aD[(size_t)row * 4 + (lr - 4)] = accL[r];
        }
    }
}

// ---------------------------------------------------------------------------
// Gather-aggregate v6: FOUR nodes per wave (quarter q owns one node; li
// owns 8 channels). Phase 1: self-loop slot 0 + ELL edges 16-wide. Phase 2:
// per-quarter dependence-free channel loop, ushort8 h loads, no cross-lane
// reduce. deg>ELLCAP (8-sigma impossible) -> full raw-edge rescan path.
// 512-thread blocks, 4 blocks/CU. Zero atomics.
// ---------------------------------------------------------------------------
__launch_bounds__(512)
__global__ void gather_kernel(const int* __restrict__ cnt,
                              const int* __restrict__ ell,
                              const int* __restrict__ ei,
                              const unsigned short* __restrict__ hb,
                              const float* __restrict__ aS,
                              const float* __restrict__ aD,
                              const float* __restrict__ bias,
                              float* __restrict__ out) {
    __shared__ int   sbuf[8][4][ELLCAP + 1];
    __shared__ float wbuf[8][4][ELLCAP + 1][4];

    const int batch = blockIdx.x & 7;                 // XCD pin: batch slab in L2
    const int wv    = threadIdx.x >> 6;               // wave 0..7
    const int lane  = threadIdx.x & 63;
    const int q     = lane >> 4;                      // quarter = node slot 0..3
    const int li    = lane & 15;
    const int base  = batch * T_LEN;
    const int nib   = ((blockIdx.x >> 3) << 5) + (wv << 2) + q;  // node in batch
    const int n     = base + nib;

    const int deg = cnt[nib];
    const int ci  = li * 8;           // 8 owned channels
    const int hh  = li >> 2;          // head of those channels

    const float4 ad4 = *(const float4*)(aD + (size_t)n * 4);

    float4 A0 = make_float4(0.f, 0.f, 0.f, 0.f);
    float4 A1 = make_float4(0.f, 0.f, 0.f, 0.f);
    float dsum = 0.f;

    if (deg <= ELLCAP) {
        // ---- phase 1: self loop -> slot 0 (li==0 of each quarter)
        if (li == 0) {
            const float4 as4 = *(const float4*)(aS + (size_t)n * 4);
            float4 l;
            l.x = as4.x + ad4.x; l.x = (l.x > 0.f) ? l.x : NEG_SLOPE * l.x;
            l.y = as4.y + ad4.y; l.y = (l.y > 0.f) ? l.y : NEG_SLOPE * l.y;
            l.z = as4.z + ad4.z; l.z = (l.z > 0.f) ? l.z : NEG_SLOPE * l.z;
            l.w = as4.w + ad4.w; l.w = (l.w > 0.f) ? l.w : NEG_SLOPE * l.w;
            sbuf[wv][q][0]    = n;
            wbuf[wv][q][0][0] = __expf(l.x);
            wbuf[wv][q][0][1] = __expf(l.y);
            wbuf[wv][q][0][2] = __expf(l.z);
            wbuf[wv][q][0][3] = __expf(l.w);
        }
        // ELL edge jj -> slot jj+1 (16-wide per quarter)
        for (int jj = li; jj < deg; jj += 16) {
            const int s = ell[nib * ELLCAP + jj] + base;
            const float4 as4 = *(const float4*)(aS + (size_t)s * 4);
            float4 l;
            l.x = as4.x + ad4.x; l.x = (l.x > 0.f) ? l.x : NEG_SLOPE * l.x;
            l.y = as4.y + ad4.y; l.y = (l.y > 0.f) ? l.y : NEG_SLOPE * l.y;
            l.z = as4.z + ad4.z; l.z = (l.z > 0.f) ? l.z : NEG_SLOPE * l.z;
            l.w = as4.w + ad4.w; l.w = (l.w > 0.f) ? l.w : NEG_SLOPE * l.w;
            sbuf[wv][q][jj + 1]    = s;
            wbuf[wv][q][jj + 1][0] = __expf(l.x);
            wbuf[wv][q][jj + 1][1] = __expf(l.y);
            wbuf[wv][q][jj + 1][2] = __expf(l.z);
            wbuf[wv][q][jj + 1][3] = __expf(l.w);
        }
        // wave-synchronous: same wave wrote, same wave reads

        // ---- phase 2: dependence-free channel accumulation
        const int nst = deg + 1;
        #pragma unroll 4
        for (int j = 0; j < nst; ++j) {
            const int   s = sbuf[wv][q][j];
            const float w = wbuf[wv][q][j][hh];
            dsum += w;
            const short8 hv = *(const short8*)(hb + (size_t)s * 128 + ci);
            A0.x += w * bf16f((unsigned short)hv[0]);
            A0.y += w * bf16f((unsigned short)hv[1]);
            A0.z += w * bf16f((unsigned short)hv[2]);
            A0.w += w * bf16f((unsigned short)hv[3]);
            A1.x += w * bf16f((unsigned short)hv[4]);
            A1.y += w * bf16f((unsigned short)hv[5]);
            A1.z += w * bf16f((unsigned short)hv[6]);
            A1.w += w * bf16f((unsigned short)hv[7]);
        }
    } else {
        // ---- 8-sigma-impossible overflow: full raw-edge rescan (correct,
        // slow, never executed for this distribution)
        int sh = 1;
        for (int t = 0; t < 64; ++t) if (ei[2 * t + 1] != 0) { sh = 0; break; }
        const float adh = (hh == 0) ? ad4.x : (hh == 1) ? ad4.y
                        : (hh == 2) ? ad4.z : ad4.w;
        // self loop
        {
            float l = aS[(size_t)n * 4 + hh] + adh;
            l = (l > 0.f) ? l : NEG_SLOPE * l;
            const float w = __expf(l);
            dsum += w;
            const short8 hv = *(const short8*)(hb + (size_t)n * 128 + ci);
            A0.x += w * bf16f((unsigned short)hv[0]);
            A0.y += w * bf16f((unsigned short)hv[1]);
            A0.z += w * bf16f((unsigned short)hv[2]);
            A0.w += w * bf16f((unsigned short)hv[3]);
            A1.x += w * bf16f((unsigned short)hv[4]);
            A1.y += w * bf16f((unsigned short)hv[5]);
            A1.z += w * bf16f((unsigned short)hv[6]);
            A1.w += w * bf16f((unsigned short)hv[7]);
        }
        for (int j = 0; j < E_EDGES; ++j) {
            const int d = ei[(E_EDGES + j) << sh];
            if (d == nib) {
                const int s = ei[j << sh] + base;
                float l = aS[(size_t)s * 4 + hh] + adh;
                l = (l > 0.f) ? l : NEG_SLOPE * l;
                const float w = __expf(l);
                dsum += w;
                const short8 hv = *(const short8*)(hb + (size_t)s * 128 + ci);
                A0.x += w * bf16f((unsigned short)hv[0]);
                A0.y += w * bf16f((unsigned short)hv[1]);
                A0.z += w * bf16f((unsigned short)hv[2]);
                A0.w += w * bf16f((unsigned short)hv[3]);
                A1.x += w * bf16f((unsigned short)hv[4]);
                A1.y += w * bf16f((unsigned short)hv[5]);
                A1.z += w * bf16f((unsigned short)hv[6]);
                A1.w += w * bf16f((unsigned short)hv[7]);
            }
        }
    }

    // finalize + write (all 64 lanes; wave covers 4 nodes = 2 KB contiguous)
    const float inv = 1.0f / (dsum + 1e-16f);
    const float4 b0 = *(const float4*)(bias + ci);
    const float4 b1 = *(const float4*)(bias + ci + 4);
    float4 o0, o1;
    o0.x = A0.x * inv + b0.x; o0.y = A0.y * inv + b0.y;
    o0.z = A0.z * inv + b0.z; o0.w = A0.w * inv + b0.w;
    o1.x = A1.x * inv + b1.x; o1.y = A1.y * inv + b1.y;
    o1.z = A1.z * inv + b1.z; o1.w = A1.w * inv + b1.w;
    float* op = out + (size_t)n * 128 + ci;
    *(float4*)(op)     = o0;
    *(float4*)(op + 4) = o1;
}

// ---------------------------------------------------------------------------
extern "C" void kernel_launch(void* const* d_in, const int* in_sizes, int n_in,
                              void* d_out, int out_size, void* d_ws, size_t ws_size,
                              hipStream_t stream) {
    const float* x    = (const float*)d_in[0];
    const int*   ei   = (const int*)  d_in[1];
    const float* W    = (const float*)d_in[2];
    const float* attS = (const float*)d_in[3];
    const float* attD = (const float*)d_in[4];
    const float* bias = (const float*)d_in[5];
    float* out = (float*)d_out;

    // workspace layout (4-byte units; base is 16B-aligned)
    float* ws = (float*)d_ws;
    unsigned short* hb = (unsigned short*)ws;            // N*128 bf16 (8 MB)
    float* aS          = ws + (size_t)N_NODES * 64;      // N*4
    float* aD          = aS + (size_t)N_NODES * 4;       // N*4
    int*   cnt         = (int*)(aD + (size_t)N_NODES * 4); // T_LEN
    int*   ell         = cnt + T_LEN;                    // T_LEN*ELLCAP

    // dispatch 1: GEMM+logits (blocks 0..511) || ELL build (blocks 512..527)
    fused_kernel<<<GEMM_BLOCKS + ELL_BLOCKS, 256, 0, stream>>>(
        x, W, attS, attD, ei, hb, aS, aD, cnt, ell);

    // dispatch 2: gather-aggregate v6
    gather_kernel<<<N_NODES / 32, 512, 0, stream>>>(cnt, ell, ei,
                                                    hb, aS, aD, bias, out);
}

// Round 18
// 37.274 us; speedup vs baseline: 4.4345x; 4.4345x over previous
//
#include <hip/hip_runtime.h>

#define BATCH    8
#define T_LEN    4096
#define D_DIM    128
#define H_HEADS  4
#define O_DIM    32
#define E_EDGES  65536
#define N_NODES  (BATCH * T_LEN)      // 32768
#define NEG_SLOPE 0.2f
#define ELLCAP   48                   // deg ~ Binom: mean 16, sd 4; 48 = 8 sigma
#define SPILLCAP 8192
#define GEMM_BLOCKS 512               // 64 rows each
#define XSTRIDE  144                  // Xb row stride in shorts (288 B, 16B-mult)
#define ATTB_COL 40                   // attB col stride (80 B)
#define ATTB_KT  320                  // attB kt stride (= 8 cols * 40)

typedef __attribute__((ext_vector_type(8))) short short8;
typedef __attribute__((ext_vector_type(4))) float f32x4;

// round-to-nearest-even fp32 -> bf16 bits
__device__ __forceinline__ unsigned int bf16b(float f) {
    unsigned int u = __float_as_uint(f);
    u += 0x7FFFu + ((u >> 16) & 1u);
    return u >> 16;
}
__device__ __forceinline__ unsigned int bf16pack(float lo, float hi) {
    return bf16b(lo) | (bf16b(hi) << 16);
}
__device__ __forceinline__ float bf16f(unsigned short u) {
    return __uint_as_float((unsigned int)u << 16);
}

// ---------------------------------------------------------------------------
// int64-vs-int32 layout detection (edge values < 4096 -> int64 odd words all 0)
// ---------------------------------------------------------------------------
__device__ __forceinline__ int detect_shift(const int* ei, int tidx, int* s_sh) {
    if (tidx < 64) {
        const int nz = (ei[2 * tidx + 1] != 0) ? 1 : 0;
        const unsigned long long b = __ballot(nz);
        if (tidx == 0) *s_sh = (b == 0ull) ? 1 : 0;
    }
    __syncthreads();
    return *s_sh;
}

// ---------------------------------------------------------------------------
// Prep: zero cnt[4096]+spill_cnt AND build global bf16 W^T (Wt[col][k]).
// Coalesced W read, conflict-free (global->global) — the R17 in-block
// transpose was a 16-way LDS bank conflict; this stays.
// ---------------------------------------------------------------------------
__launch_bounds__(256)
__global__ void prep_kernel(const float* __restrict__ W,
                            int* __restrict__ cnt,
                            unsigned short* __restrict__ WtG) {
    const int g = blockIdx.x * 256 + threadIdx.x;
    if (g < T_LEN + 1) cnt[g] = 0;                       // cnt + spill_cnt
    const int i = g - 4352;
    if (i >= 0 && i < 128 * 128) {
        const int k   = i >> 7;
        const int col = i & 127;                         // coalesced W read
        WtG[col * 128 + k] = (unsigned short)bf16b(W[k * 128 + col]);
    }
}

// ---------------------------------------------------------------------------
// Fused: blocks [0,512) = bf16-MFMA GEMM h=X*W + MFMA logits (64 rows/block,
// ~53 KB LDS -> 3 blocks/CU); blocks [512,768) = ELL build (256 blocks,
// global atomics — full parallelism, no long tail; R17's 16-block windowed
// scan collapsed occupancy).
// MFMA fragment layout (m97-lineage, ref-checked): A[l&15][k0+(l>>4)*8+j],
// B = Wt[col l&15][same ks], D: row=(lg*4+r), col=cf*16+lr.
// ---------------------------------------------------------------------------
__launch_bounds__(256)
__global__ void gemm_ell_kernel(const float* __restrict__ x,
                                const unsigned short* __restrict__ WtG,
                                const float* __restrict__ attS,
                                const float* __restrict__ attD,
                                const int* __restrict__ ei,
                                unsigned short* __restrict__ hb,
                                float* __restrict__ aS,
                                float* __restrict__ aD,
                                int* __restrict__ cnt,
                                int* __restrict__ ell,
                                int* __restrict__ spill_cnt,
                                int2* __restrict__ spill) {
    __shared__ __align__(16) short Xb[64][XSTRIDE]; // X tile, then h staging
    __shared__ __align__(16) short Wt[128][136];    // cols x k bf16; tail reused
    __shared__ int   s_sh;

    const int tid = threadIdx.x;

    if (blockIdx.x >= GEMM_BLOCKS) {
        // ---------------- ELL build branch ----------------
        const int sh = detect_shift(ei, tid, &s_sh);
        const int j  = (blockIdx.x - GEMM_BLOCKS) * 256 + tid;  // covers E_EDGES
        const int s  = ei[j << sh];
        const int d  = ei[(E_EDGES + j) << sh];
        const int p  = atomicAdd(&cnt[d], 1);
        if (p < ELLCAP) {
            ell[d * ELLCAP + p] = s;
        } else {
            const int q = atomicAdd(spill_cnt, 1);
            if (q < SPILLCAP) spill[q] = make_int2(s, d);
        }
        return;
    }

    // ---------------- GEMM branch ----------------
    // batch = blk%8 (XCD pin), 64-row tile = blk/8
    const int row0 = (blockIdx.x & 7) * T_LEN + ((blockIdx.x >> 3) << 6);

    // stage X tile (64x128 fp32 -> bf16), coalesced float4 reads
    const float4* X4 = (const float4*)(x + (size_t)row0 * 128);
    #pragma unroll
    for (int i = 0; i < 8; ++i) {
        const int idx = tid + 256 * i;
        const int row = idx >> 5;
        const int c4  = (idx & 31) * 4;
        const float4 v = X4[idx];
        uint2 u;
        u.x = bf16pack(v.x, v.y);
        u.y = bf16pack(v.z, v.w);
        *(uint2*)&Xb[row][c4] = u;
    }

    // stage Wt (already bf16+transposed in global), coalesced short8 loads
    #pragma unroll
    for (int i = 0; i < 8; ++i) {
        const int idx = tid + 256 * i;          // 2048 chunks of 8 shorts
        const int row = idx >> 4;
        const int off = (idx & 15) * 8;
        *(short8*)&Wt[row][off] = *(const short8*)&WtG[row * 128 + off];
    }
    __syncthreads();

    const int wv    = tid >> 6;        // wave 0..3 -> rows wv*16..+16
    const int l     = tid & 63;
    const int lr    = l & 15;
    const int lg    = l >> 4;
    const int wrow0 = wv * 16;

    f32x4 acc[8];
    #pragma unroll
    for (int cf = 0; cf < 8; ++cf) acc[cf] = (f32x4){0.f, 0.f, 0.f, 0.f};

    #pragma unroll
    for (int kt = 0; kt < 4; ++kt) {
        const int k0 = kt * 32 + lg * 8;
        const short8 a = *(const short8*)&Xb[wrow0 + lr][k0];
        #pragma unroll
        for (int cf = 0; cf < 8; ++cf) {
            const short8 b = *(const short8*)&Wt[cf * 16 + lr][k0];
            acc[cf] = __builtin_amdgcn_mfma_f32_16x16x32_bf16(a, b, acc[cf], 0, 0, 0);
        }
    }

    __syncthreads();   // all waves done reading Xb (A) and Wt (B)

    // scatter bf16 h into Xb (stride 144 -> rows rotate 8 banks, <=2-way)
    #pragma unroll
    for (int cf = 0; cf < 8; ++cf) {
        #pragma unroll
        for (int r = 0; r < 4; ++r)
            Xb[wrow0 + lg * 4 + r][cf * 16 + lr] = (short)bf16b(acc[cf][r]);
    }

    // build block-diagonal att table in dead Wt space:
    // col 0-3 = attS head col (nonzero iff kt==col), col 4-7 = attD head col-4
    short* attB = &Wt[0][0];
    #pragma unroll
    for (int e = 0; e < 5; ++e) {
        const int idx = tid * 5 + e;            // 1280 entries
        const int kt  = idx / ATTB_KT;
        const int rem = idx - kt * ATTB_KT;
        const int col = rem / ATTB_COL;
        const int kk  = rem - col * ATTB_COL;
        float v = 0.f;
        if (kk < 32) {
            if (col < 4) v = (kt == col)     ? attS[col * 32 + kk]       : 0.f;
            else         v = (kt == col - 4) ? attD[(col - 4) * 32 + kk] : 0.f;
        }
        attB[idx] = (short)bf16b(v);
    }
    __syncthreads();

    // coalesced h stores (1 KB/instruction)
    #pragma unroll
    for (int i = 0; i < 4; ++i) {
        const int idx = tid + 256 * i;          // 1024 chunks of 8 shorts
        const int row = idx >> 4;
        const int off = (idx & 15) * 8;
        *(short8*)&hb[(size_t)(row0 + row) * 128 + off] =
            *(const short8*)&Xb[row][off];
    }

    // logits via MFMA: accL[row][col] = sum_k h[row][k]*attB[col][k]
    f32x4 accL = (f32x4){0.f, 0.f, 0.f, 0.f};
    #pragma unroll
    for (int kt = 0; kt < 4; ++kt) {
        const short8 a2 = *(const short8*)&Xb[wrow0 + lr][kt * 32 + lg * 8];
        const short8 b2 = *(const short8*)&attB[kt * ATTB_KT + (lr & 7) * ATTB_COL + lg * 8];
        accL = __builtin_amdgcn_mfma_f32_16x16x32_bf16(a2, b2, accL, 0, 0, 0);
    }
    if (lr < 8) {
        #pragma unroll
        for (int r = 0; r < 4; ++r) {
            const int row = row0 + wrow0 + lg * 4 + r;
            if (lr < 4) aS[(size_t)row * 4 + lr]       = accL[r];
            else        aD[(size_t)row * 4 + (lr - 4)] = accL[r];
        }
    }
}

// ---------------------------------------------------------------------------
// Gather-aggregate v6: FOUR nodes per wave (quarter q owns one node; li
// owns 8 channels). Phase 1: self-loop slot 0 + ELL edges 16-wide. Phase 2:
// per-quarter dependence-free channel loop, ushort8 h loads, no cross-lane
// reduce. 512-thread blocks, 4 blocks/CU. Zero atomics, spill fallback.
// ---------------------------------------------------------------------------
__launch_bounds__(512)
__global__ void gather_kernel(const int* __restrict__ cnt,
                              const int* __restrict__ ell,
                              const int* __restrict__ spill_cnt,
                              const int2* __restrict__ spill,
                              const unsigned short* __restrict__ hb,
                              const float* __restrict__ aS,
                              const float* __restrict__ aD,
                              const float* __restrict__ bias,
                              float* __restrict__ out) {
    __shared__ int   sbuf[8][4][ELLCAP + 1];
    __shared__ float wbuf[8][4][ELLCAP + 1][4];

    const int batch = blockIdx.x & 7;                 // XCD pin: batch slab in L2
    const int wv    = threadIdx.x >> 6;               // wave 0..7
    const int lane  = threadIdx.x & 63;
    const int q     = lane >> 4;                      // quarter = node slot 0..3
    const int li    = lane & 15;
    const int base  = batch * T_LEN;
    const int nib   = ((blockIdx.x >> 3) << 5) + (wv << 2) + q;  // node in batch
    const int n     = base + nib;

    const int deg = cnt[nib];
    const int m   = (deg < ELLCAP) ? deg : ELLCAP;    // staged edge count

    const float4 ad4 = *(const float4*)(aD + (size_t)n * 4);

    // ---- phase 1: self loop -> slot 0 (li==0 of each quarter)
    if (li == 0) {
        const float4 as4 = *(const float4*)(aS + (size_t)n * 4);
        float4 l;
        l.x = as4.x + ad4.x; l.x = (l.x > 0.f) ? l.x : NEG_SLOPE * l.x;
        l.y = as4.y + ad4.y; l.y = (l.y > 0.f) ? l.y : NEG_SLOPE * l.y;
        l.z = as4.z + ad4.z; l.z = (l.z > 0.f) ? l.z : NEG_SLOPE * l.z;
        l.w = as4.w + ad4.w; l.w = (l.w > 0.f) ? l.w : NEG_SLOPE * l.w;
        sbuf[wv][q][0]    = n;
        wbuf[wv][q][0][0] = __expf(l.x);
        wbuf[wv][q][0][1] = __expf(l.y);
        wbuf[wv][q][0][2] = __expf(l.z);
        wbuf[wv][q][0][3] = __expf(l.w);
    }
    // ELL edge jj -> slot jj+1 (16-wide per quarter; 2nd pass if deg>16)
    for (int jj = li; jj < m; jj += 16) {
        const int s = ell[nib * ELLCAP + jj] + base;
        const float4 as4 = *(const float4*)(aS + (size_t)s * 4);
        float4 l;
        l.x = as4.x + ad4.x; l.x = (l.x > 0.f) ? l.x : NEG_SLOPE * l.x;
        l.y = as4.y + ad4.y; l.y = (l.y > 0.f) ? l.y : NEG_SLOPE * l.y;
        l.z = as4.z + ad4.z; l.z = (l.z > 0.f) ? l.z : NEG_SLOPE * l.z;
        l.w = as4.w + ad4.w; l.w = (l.w > 0.f) ? l.w : NEG_SLOPE * l.w;
        sbuf[wv][q][jj + 1]    = s;
        wbuf[wv][q][jj + 1][0] = __expf(l.x);
        wbuf[wv][q][jj + 1][1] = __expf(l.y);
        wbuf[wv][q][jj + 1][2] = __expf(l.z);
        wbuf[wv][q][jj + 1][3] = __expf(l.w);
    }
    // wave-synchronous: same wave wrote, same wave reads (DS ops in order)

    // ---- phase 2: each quarter accumulates its own node
    const int ci = li * 8;            // 8 owned channels
    const int hh = li >> 2;           // head of those channels

    float4 A0 = make_float4(0.f, 0.f, 0.f, 0.f);
    float4 A1 = make_float4(0.f, 0.f, 0.f, 0.f);
    float dsum = 0.f;
    const int nst = m + 1;
    #pragma unroll 4
    for (int j = 0; j < nst; ++j) {
        const int   s = sbuf[wv][q][j];
        const float w = wbuf[wv][q][j][hh];
        dsum += w;
        const short8 hv = *(const short8*)(hb + (size_t)s * 128 + ci);
        A0.x += w * bf16f((unsigned short)hv[0]);
        A0.y += w * bf16f((unsigned short)hv[1]);
        A0.z += w * bf16f((unsigned short)hv[2]);
        A0.w += w * bf16f((unsigned short)hv[3]);
        A1.x += w * bf16f((unsigned short)hv[4]);
        A1.y += w * bf16f((unsigned short)hv[5]);
        A1.z += w * bf16f((unsigned short)hv[6]);
        A1.w += w * bf16f((unsigned short)hv[7]);
    }

    // ---- spill fallback (per quarter; count is 0 for this data)
    int sc = *spill_cnt;
    if (sc > 0) {
        if (sc > SPILLCAP) sc = SPILLCAP;
        const float adh = (hh == 0) ? ad4.x : (hh == 1) ? ad4.y
                        : (hh == 2) ? ad4.z : ad4.w;
        for (int p = 0; p < sc; ++p) {
            const int2 e = spill[p];
            if (e.y == nib) {
                const int s = e.x + base;
                float l = aS[(size_t)s * 4 + hh] + adh;
                l = (l > 0.f) ? l : NEG_SLOPE * l;
                const float w = __expf(l);
                dsum += w;
                const short8 hv = *(const short8*)(hb + (size_t)s * 128 + ci);
                A0.x += w * bf16f((unsigned short)hv[0]);
                A0.y += w * bf16f((unsigned short)hv[1]);
                A0.z += w * bf16f((unsigned short)hv[2]);
                A0.w += w * bf16f((unsigned short)hv[3]);
                A1.x += w * bf16f((unsigned short)hv[4]);
                A1.y += w * bf16f((unsigned short)hv[5]);
                A1.z += w * bf16f((unsigned short)hv[6]);
                A1.w += w * bf16f((unsigned short)hv[7]);
            }
        }
    }

    // finalize + write (all 64 lanes; wave covers 4 nodes = 2 KB contiguous)
    const float inv = 1.0f / (dsum + 1e-16f);
    const float4 b0 = *(const float4*)(bias + ci);
    const float4 b1 = *(const float4*)(bias + ci + 4);
    float4 o0, o1;
    o0.x = A0.x * inv + b0.x; o0.y = A0.y * inv + b0.y;
    o0.z = A0.z * inv + b0.z; o0.w = A0.w * inv + b0.w;
    o1.x = A1.x * inv + b1.x; o1.y = A1.y * inv + b1.y;
    o1.z = A1.z * inv + b1.z; o1.w = A1.w * inv + b1.w;
    float* op = out + (size_t)n * 128 + ci;
    *(float4*)(op)     = o0;
    *(float4*)(op + 4) = o1;
}

// ---------------------------------------------------------------------------
extern "C" void kernel_launch(void* const* d_in, const int* in_sizes, int n_in,
                              void* d_out, int out_size, void* d_ws, size_t ws_size,
                              hipStream_t stream) {
    const float* x    = (const float*)d_in[0];
    const int*   ei   = (const int*)  d_in[1];
    const float* W    = (const float*)d_in[2];
    const float* attS = (const float*)d_in[3];
    const float* attD = (const float*)d_in[4];
    const float* bias = (const float*)d_in[5];
    float* out = (float*)d_out;

    // workspace layout (4-byte units; base is 16B-aligned)
    float* ws = (float*)d_ws;
    unsigned short* hb  = (unsigned short*)ws;               // N*128 bf16 (8 MB)
    float* aS           = ws + (size_t)N_NODES * 64;         // N*4
    float* aD           = aS + (size_t)N_NODES * 4;          // N*4
    unsigned short* WtG = (unsigned short*)(aD + (size_t)N_NODES * 4);  // 128*128 bf16
    int*   cnt          = (int*)(WtG + 128 * 128);           // T_LEN
    int*   spill_cnt    = cnt + T_LEN;                       // 1 (+1 pad)
    int*   ell          = spill_cnt + 2;                     // T_LEN*ELLCAP
    int2*  spill        = (int2*)(ell + T_LEN * ELLCAP);     // SPILLCAP int2

    // prep: zero cnt/spill_cnt + build bf16 W^T
    prep_kernel<<<81, 256, 0, stream>>>(W, cnt, WtG);

    // fused: MFMA GEMM + logits (blocks 0..511) || ELL build (blocks 512..767)
    gemm_ell_kernel<<<GEMM_BLOCKS + 256, 256, 0, stream>>>(
        x, WtG, attS, attD, ei, hb, aS, aD, cnt, ell, spill_cnt, spill);

    // gather-aggregate v6: 4 nodes/wave, 512-thread blocks, full occupancy
    gather_kernel<<<N_NODES / 32, 512, 0, stream>>>(cnt, ell, spill_cnt, spill,
                                                    hb, aS, aD, bias, out);
}